// Round 1
// 91.795 us; speedup vs baseline: 1.0489x; 1.0489x over previous
//
#include <hip/hip_runtime.h>

// RBF: out[b,l] = exp(-(1/256) * max(||x_b||^2 + ||l_l||^2 - 2 x_b·l_l, 0))
// B=8192, L=2048, D=256. bf16 MFMA GEMM + fused epilogue.
// R1: double-buffered LDS + counted vmcnt(8) pipeline (T3/T4 minimum 2-phase),
//     raw asm barriers (no compiler vmcnt(0) drain), fused cvt launches.

typedef __bf16 bf16x8 __attribute__((ext_vector_type(8)));
typedef float  f32x4  __attribute__((ext_vector_type(4)));

#define B_ROWS 8192
#define L_ROWS 2048
#define K_DIM  256

#define GLD_LDS(g, l) __builtin_amdgcn_global_load_lds(                      \
    (const __attribute__((address_space(1))) void*)(g),                      \
    (__attribute__((address_space(3))) void*)(l), 16, 0, 0)

__device__ __forceinline__ unsigned short f32_to_bf16_rne(float f) {
    union { float f; unsigned int u; } v; v.f = f;
    unsigned int u = v.u;
    unsigned int r = (u + 0x7fffu + ((u >> 16) & 1u)) >> 16;
    return (unsigned short)r;
}

// One wave per 256-float row: convert to bf16 (RNE) + fp32 squared-norm.
// Fused: first B_ROWS waves handle x, remaining L_ROWS waves handle landmarks.
__global__ __launch_bounds__(256) void cvt_rows_kernel(
    const float* __restrict__ x, const float* __restrict__ lm,
    unsigned short* __restrict__ xb, unsigned short* __restrict__ lb,
    float* __restrict__ x2, float* __restrict__ l2)
{
    const int lane = threadIdx.x & 63;
    const int gw   = blockIdx.x * 4 + (threadIdx.x >> 6);
    const float* in; unsigned short* outb; float* sq; int row;
    if (gw < B_ROWS) { in = x;  outb = xb; sq = x2; row = gw; }           // wave-uniform branch
    else             { in = lm; outb = lb; sq = l2; row = gw - B_ROWS; }
    const float4 v = ((const float4*)(in + (size_t)row * K_DIM))[lane];
    ushort4 o;
    o.x = f32_to_bf16_rne(v.x);
    o.y = f32_to_bf16_rne(v.y);
    o.z = f32_to_bf16_rne(v.z);
    o.w = f32_to_bf16_rne(v.w);
    ((ushort4*)(outb + (size_t)row * K_DIM))[lane] = o;
    float s = v.x*v.x + v.y*v.y + v.z*v.z + v.w*v.w;
    #pragma unroll
    for (int off = 32; off > 0; off >>= 1) s += __shfl_down(s, off, 64);
    if (lane == 0) sq[row] = s;
}

// 128x128 tile GEMM, NT layout (A [M,K] row-major, B [N,K] row-major),
// 4 waves in 2x2, each wave 64x64 via 4x4 of 16x16x32 bf16 MFMA. BK=64.
// Double-buffered LDS; next K-tile staged before compute; counted vmcnt.
__global__ __launch_bounds__(256) void rbf_gemm_kernel(
    const unsigned short* __restrict__ A,   // bf16 bits [8192][256]
    const unsigned short* __restrict__ Bm,  // bf16 bits [2048][256]
    const float* __restrict__ x2,
    const float* __restrict__ l2,
    float* __restrict__ out)                // [8192][2048]
{
    __shared__ unsigned short As[2][128 * 64];  // 2 x 16 KB
    __shared__ unsigned short Bs[2][128 * 64];  // 2 x 16 KB

    const int tid  = threadIdx.x;
    const int wave = tid >> 6;
    const int lane = tid & 63;
    const int wm = wave >> 1, wn = wave & 1;
    const int bm = blockIdx.x, bn = blockIdx.y;

    f32x4 acc[4][4];
    #pragma unroll
    for (int i = 0; i < 4; ++i)
        #pragma unroll
        for (int j = 0; j < 4; ++j)
            acc[i][j] = (f32x4){0.f, 0.f, 0.f, 0.f};

    // Staging: per wave-load, lane l writes LDS base + l*16 bytes (HW rule)
    // == row l/8, bytes (l&7)*16 — matches the global addressing below.
    // LDS is unpadded row-major [row][64] per buffer.
    const int ldrow = lane >> 3;        // 0..7 rows per wave-load
    const int ldcol = (lane & 7) * 8;   // bf16 element offset in 64-wide tile

    const unsigned short* Ab = A  + (size_t)(bm * 128) * K_DIM;
    const unsigned short* Bb = Bm + (size_t)(bn * 128) * K_DIM;

    // 8 global_load_lds per wave per stage (4 it x 2 arrays).
#define STAGE(buf, k0)                                                       \
    _Pragma("unroll")                                                        \
    for (int it = 0; it < 4; ++it) {                                         \
        const int r = wave * 32 + it * 8;                                    \
        GLD_LDS(Ab + (r + ldrow) * K_DIM + (k0) + ldcol, &As[buf][r * 64]);  \
        GLD_LDS(Bb + (r + ldrow) * K_DIM + (k0) + ldcol, &Bs[buf][r * 64]);  \
    }

    STAGE(0, 0);

    #pragma unroll
    for (int t = 0; t < 4; ++t) {       // K_DIM/64 = 4 K-steps
        const int cur = t & 1;
        if (t < 3) { STAGE(cur ^ 1, (t + 1) * 64); }
        // Counted wait: the 8 newest (next-tile) loads may stay in flight;
        // everything older (this tile's 8) is complete. Never vmcnt(0) mid-loop.
        if (t < 3) asm volatile("s_waitcnt vmcnt(8)" ::: "memory");
        else       asm volatile("s_waitcnt vmcnt(0)" ::: "memory");
        asm volatile("s_barrier" ::: "memory");   // all waves' stage(t) done

        #pragma unroll
        for (int kk = 0; kk < 64; kk += 32) {
            const int ko = kk + (lane >> 4) * 8;   // A/B frag: k = quad*8 + j
            bf16x8 af[4], bfr[4];
            #pragma unroll
            for (int tt = 0; tt < 4; ++tt) {
                af[tt]  = *(const bf16x8*)&As[cur][(wm*64 + tt*16 + (lane & 15)) * 64 + ko];
                bfr[tt] = *(const bf16x8*)&Bs[cur][(wn*64 + tt*16 + (lane & 15)) * 64 + ko];
            }
            #pragma unroll
            for (int mt = 0; mt < 4; ++mt)
                #pragma unroll
                for (int nt = 0; nt < 4; ++nt)
                    acc[mt][nt] = __builtin_amdgcn_mfma_f32_16x16x32_bf16(
                        af[mt], bfr[nt], acc[mt][nt], 0, 0, 0);
        }
        // Protect buf[cur] from being overwritten by t+1's STAGE (which
        // targets buf[(t+2)&1] == buf[cur]).
        if (t < 3) asm volatile("s_barrier" ::: "memory");
    }
#undef STAGE

    // Epilogue: C/D layout col=lane&15, row=(lane>>4)*4+reg (m89-verified).
    const float gamma = 1.0f / 256.0f;
    const int col0 = bn * 128 + wn * 64 + (lane & 15);
    const int row0 = bm * 128 + wm * 64 + (lane >> 4) * 4;
    #pragma unroll
    for (int mt = 0; mt < 4; ++mt) {
        const int rb = row0 + mt * 16;
        float xv[4];
        #pragma unroll
        for (int r = 0; r < 4; ++r) xv[r] = x2[rb + r];
        #pragma unroll
        for (int nt = 0; nt < 4; ++nt) {
            const int c  = col0 + nt * 16;
            const float lv = l2[c];
            #pragma unroll
            for (int r = 0; r < 4; ++r) {
                float d2 = fmaxf(xv[r] + lv - 2.0f * acc[mt][nt][r], 0.0f);
                out[(size_t)(rb + r) * L_ROWS + c] = __expf(-gamma * d2);
            }
        }
    }
}

extern "C" void kernel_launch(void* const* d_in, const int* in_sizes, int n_in,
                              void* d_out, int out_size, void* d_ws, size_t ws_size,
                              hipStream_t stream) {
    const float* x  = (const float*)d_in[0];   // [8192, 256]
    const float* lm = (const float*)d_in[1];   // [2048, 256]
    float* out = (float*)d_out;

    char* ws = (char*)d_ws;
    unsigned short* xb = (unsigned short*)ws;                               // 4 MB
    unsigned short* lb = (unsigned short*)(ws + (size_t)B_ROWS*K_DIM*2);    // 1 MB
    float* x2 = (float*)(ws + (size_t)B_ROWS*K_DIM*2 + (size_t)L_ROWS*K_DIM*2);
    float* l2 = x2 + B_ROWS;

    cvt_rows_kernel<<<(B_ROWS + L_ROWS)/4, 256, 0, stream>>>(x, lm, xb, lb, x2, l2);
    rbf_gemm_kernel<<<dim3(B_ROWS/128, L_ROWS/128), 256, 0, stream>>>(xb, lb, x2, l2, out);
}

// Round 2
// 90.647 us; speedup vs baseline: 1.0622x; 1.0127x over previous
//
#include <hip/hip_runtime.h>

// RBF: out[b,l] = exp(-(1/256) * max(||x_b||^2 + ||l_l||^2 - 2 x_b·l_l, 0))
// B=8192, L=2048, D=256. bf16 MFMA GEMM + fused epilogue.
// R1: double-buffered LDS + counted vmcnt(8) pipeline (kept).
// R2: T2 XOR-swizzle on LDS tiles (st_16x32 style). Read was 16-way bank
//     conflicted (128 B row stride, lanes 0-15 same bank group). Fix per
//     rule #21: linear global_load_lds dest + pre-swizzled per-lane GLOBAL
//     source granule + same XOR on ds_read offset.

typedef __bf16 bf16x8 __attribute__((ext_vector_type(8)));
typedef float  f32x4  __attribute__((ext_vector_type(4)));

#define B_ROWS 8192
#define L_ROWS 2048
#define K_DIM  256

#define GLD_LDS(g, l) __builtin_amdgcn_global_load_lds(                      \
    (const __attribute__((address_space(1))) void*)(g),                      \
    (__attribute__((address_space(3))) void*)(l), 16, 0, 0)

__device__ __forceinline__ unsigned short f32_to_bf16_rne(float f) {
    union { float f; unsigned int u; } v; v.f = f;
    unsigned int u = v.u;
    unsigned int r = (u + 0x7fffu + ((u >> 16) & 1u)) >> 16;
    return (unsigned short)r;
}

// One wave per 256-float row: convert to bf16 (RNE) + fp32 squared-norm.
// Fused: first B_ROWS waves handle x, remaining L_ROWS waves handle landmarks.
__global__ __launch_bounds__(256) void cvt_rows_kernel(
    const float* __restrict__ x, const float* __restrict__ lm,
    unsigned short* __restrict__ xb, unsigned short* __restrict__ lb,
    float* __restrict__ x2, float* __restrict__ l2)
{
    const int lane = threadIdx.x & 63;
    const int gw   = blockIdx.x * 4 + (threadIdx.x >> 6);
    const float* in; unsigned short* outb; float* sq; int row;
    if (gw < B_ROWS) { in = x;  outb = xb; sq = x2; row = gw; }           // wave-uniform branch
    else             { in = lm; outb = lb; sq = l2; row = gw - B_ROWS; }
    const float4 v = ((const float4*)(in + (size_t)row * K_DIM))[lane];
    ushort4 o;
    o.x = f32_to_bf16_rne(v.x);
    o.y = f32_to_bf16_rne(v.y);
    o.z = f32_to_bf16_rne(v.z);
    o.w = f32_to_bf16_rne(v.w);
    ((ushort4*)(outb + (size_t)row * K_DIM))[lane] = o;
    float s = v.x*v.x + v.y*v.y + v.z*v.z + v.w*v.w;
    #pragma unroll
    for (int off = 32; off > 0; off >>= 1) s += __shfl_down(s, off, 64);
    if (lane == 0) sq[row] = s;
}

// 128x128 tile GEMM, NT layout (A [M,K] row-major, B [N,K] row-major),
// 4 waves in 2x2, each wave 64x64 via 4x4 of 16x16x32 bf16 MFMA. BK=64.
// Double-buffered LDS; next K-tile staged before compute; counted vmcnt.
// LDS layout: XOR-swizzled — LDS[row R][granule g] = global[R][g ^ (R&7)],
// granule = 16 B (8 bf16). Staging realizes this by pre-swizzling the
// per-lane global source (dest stays linear, HW rule); reads XOR the
// within-row byte offset with (R&7)<<4. R&7 == lane-derived on both sides.
__global__ __launch_bounds__(256) void rbf_gemm_kernel(
    const unsigned short* __restrict__ A,   // bf16 bits [8192][256]
    const unsigned short* __restrict__ Bm,  // bf16 bits [2048][256]
    const float* __restrict__ x2,
    const float* __restrict__ l2,
    float* __restrict__ out)                // [8192][2048]
{
    __shared__ unsigned short As[2][128 * 64];  // 2 x 16 KB
    __shared__ unsigned short Bs[2][128 * 64];  // 2 x 16 KB

    const int tid  = threadIdx.x;
    const int wave = tid >> 6;
    const int lane = tid & 63;
    const int wm = wave >> 1, wn = wave & 1;
    const int bm = blockIdx.x, bn = blockIdx.y;

    f32x4 acc[4][4];
    #pragma unroll
    for (int i = 0; i < 4; ++i)
        #pragma unroll
        for (int j = 0; j < 4; ++j)
            acc[i][j] = (f32x4){0.f, 0.f, 0.f, 0.f};

    // Staging: per wave-load, lane l writes LDS base + l*16 bytes (HW rule)
    // == row (l>>3) of the 8-row group, granule (l&7). Source granule is
    // XOR'd with the row-within-group (l>>3) == (R&7) since row groups are
    // 8-aligned. This realizes the swizzled layout with a linear dest.
    const int ldrow = lane >> 3;                         // 0..7 rows per wave-load
    const int ldcol = (((lane & 7) ^ ldrow) * 8);        // swizzled source granule

    const unsigned short* Ab = A  + (size_t)(bm * 128) * K_DIM;
    const unsigned short* Bb = Bm + (size_t)(bn * 128) * K_DIM;

    // 8 global_load_lds per wave per stage (4 it x 2 arrays).
#define STAGE(buf, k0)                                                       \
    _Pragma("unroll")                                                        \
    for (int it = 0; it < 4; ++it) {                                         \
        const int r = wave * 32 + it * 8;                                    \
        GLD_LDS(Ab + (r + ldrow) * K_DIM + (k0) + ldcol, &As[buf][r * 64]);  \
        GLD_LDS(Bb + (r + ldrow) * K_DIM + (k0) + ldcol, &Bs[buf][r * 64]);  \
    }

    STAGE(0, 0);

    const int xr = (lane & 7) << 4;    // read-side XOR (bytes) == (R&7)<<4

    #pragma unroll
    for (int t = 0; t < 4; ++t) {       // K_DIM/64 = 4 K-steps
        const int cur = t & 1;
        if (t < 3) { STAGE(cur ^ 1, (t + 1) * 64); }
        // Counted wait: the 8 newest (next-tile) loads may stay in flight;
        // everything older (this tile's 8) is complete. Never vmcnt(0) mid-loop.
        if (t < 3) asm volatile("s_waitcnt vmcnt(8)" ::: "memory");
        else       asm volatile("s_waitcnt vmcnt(0)" ::: "memory");
        asm volatile("s_barrier" ::: "memory");   // all waves' stage(t) done

        #pragma unroll
        for (int kk = 0; kk < 64; kk += 32) {
            // Within-row byte offset before swizzle: kk*2 + quad*16.
            const int osw = ((kk * 2 + (lane >> 4) * 16) ^ xr) >> 1;  // elems
            bf16x8 af[4], bfr[4];
            #pragma unroll
            for (int tt = 0; tt < 4; ++tt) {
                af[tt]  = *(const bf16x8*)&As[cur][(wm*64 + tt*16 + (lane & 15)) * 64 + osw];
                bfr[tt] = *(const bf16x8*)&Bs[cur][(wn*64 + tt*16 + (lane & 15)) * 64 + osw];
            }
            #pragma unroll
            for (int mt = 0; mt < 4; ++mt)
                #pragma unroll
                for (int nt = 0; nt < 4; ++nt)
                    acc[mt][nt] = __builtin_amdgcn_mfma_f32_16x16x32_bf16(
                        af[mt], bfr[nt], acc[mt][nt], 0, 0, 0);
        }
        // Protect buf[cur] from being overwritten by t+1's STAGE (which
        // targets buf[(t+2)&1] == buf[cur]).
        if (t < 3) asm volatile("s_barrier" ::: "memory");
    }
#undef STAGE

    // Epilogue: C/D layout col=lane&15, row=(lane>>4)*4+reg (m89-verified).
    const float gamma = 1.0f / 256.0f;
    const int col0 = bn * 128 + wn * 64 + (lane & 15);
    const int row0 = bm * 128 + wm * 64 + (lane >> 4) * 4;
    #pragma unroll
    for (int mt = 0; mt < 4; ++mt) {
        const int rb = row0 + mt * 16;
        float xv[4];
        #pragma unroll
        for (int r = 0; r < 4; ++r) xv[r] = x2[rb + r];
        #pragma unroll
        for (int nt = 0; nt < 4; ++nt) {
            const int c  = col0 + nt * 16;
            const float lv = l2[c];
            #pragma unroll
            for (int r = 0; r < 4; ++r) {
                float d2 = fmaxf(xv[r] + lv - 2.0f * acc[mt][nt][r], 0.0f);
                out[(size_t)(rb + r) * L_ROWS + c] = __expf(-gamma * d2);
            }
        }
    }
}

extern "C" void kernel_launch(void* const* d_in, const int* in_sizes, int n_in,
                              void* d_out, int out_size, void* d_ws, size_t ws_size,
                              hipStream_t stream) {
    const float* x  = (const float*)d_in[0];   // [8192, 256]
    const float* lm = (const float*)d_in[1];   // [2048, 256]
    float* out = (float*)d_out;

    char* ws = (char*)d_ws;
    unsigned short* xb = (unsigned short*)ws;                               // 4 MB
    unsigned short* lb = (unsigned short*)(ws + (size_t)B_ROWS*K_DIM*2);    // 1 MB
    float* x2 = (float*)(ws + (size_t)B_ROWS*K_DIM*2 + (size_t)L_ROWS*K_DIM*2);
    float* l2 = x2 + B_ROWS;

    cvt_rows_kernel<<<(B_ROWS + L_ROWS)/4, 256, 0, stream>>>(x, lm, xb, lb, x2, l2);
    rbf_gemm_kernel<<<dim3(B_ROWS/128, L_ROWS/128), 256, 0, stream>>>(xb, lb, x2, l2, out);
}